// Round 1
// baseline (478.389 us; speedup 1.0000x reference)
//
#include <hip/hip_runtime.h>

// Problem constants (from reference)
constexpr int   NPTS   = 65536;
constexpr int   NVIEWS = 16;
constexpr int   SZ     = 400;          // IMG_SIZE
constexpr int   PAD    = 5;            // PADDING
constexpr int   HP     = SZ + 2 * PAD; // 410
constexpr float FOCAL  = 555.555f;
constexpr float SCALE  = 409.0f / 410.0f;  // (Hp-1)/Hp

constexpr long long FEATS_N = (long long)NPTS * NVIEWS * 3 * 25;  // 78,643,200

// ---------------------------------------------------------------------------
// Setup: per-view combined projection KM = K @ inv(pose @ flip)[:3,:]
// pose is rigid: c2w = [x|y|z|t; 0 0 0 1], flip negates column 0.
// A = pose@flip = [(-x)|y|z|t], A3 orthonormal -> inv(A) = [A3^T | -A3^T t].
// ---------------------------------------------------------------------------
__global__ void setup_km(const float* __restrict__ poses, float* __restrict__ km) {
    int n = threadIdx.x;
    if (n >= NVIEWS) return;
    const float* A = poses + n * 16;  // row-major 4x4
    // columns of rotation
    float x0 = A[0], x1 = A[4], x2 = A[8];
    float y0 = A[1], y1 = A[5], y2 = A[9];
    float z0 = A[2], z1 = A[6], z2 = A[10];
    float t0 = A[3], t1 = A[7], t2 = A[11];

    float M0[4] = { -x0, -x1, -x2,  (x0 * t0 + x1 * t1 + x2 * t2) };
    float M1[4] = {  y0,  y1,  y2, -(y0 * t0 + y1 * t1 + y2 * t2) };
    float M2[4] = {  z0,  z1,  z2, -(z0 * t0 + z1 * t1 + z2 * t2) };

    const float f = FOCAL, cx = 0.5f * SZ;
    float* o = km + n * 12;
#pragma unroll
    for (int k = 0; k < 4; ++k) o[k]     = f * M0[k] + cx * M2[k];
#pragma unroll
    for (int k = 0; k < 4; ++k) o[4 + k] = f * M1[k] + cx * M2[k];
#pragma unroll
    for (int k = 0; k < 4; ++k) o[8 + k] = M2[k];
}

// ---------------------------------------------------------------------------
// Gated 3-channel fetch from the (conceptually padded) image.
// r,c are ORIGINAL-image indices (padded index minus PAD). Out of [0,400)
// means padding -> 0. The reference's extra valid mask (ri in [0,410)) is
// always true for clipped projections, so it is omitted.
// ---------------------------------------------------------------------------
__device__ __forceinline__ void fetch3(const float* __restrict__ ib, int r, int c,
                                       float& a, float& b, float& d) {
    bool ok = ((unsigned)r < (unsigned)SZ) & ((unsigned)c < (unsigned)SZ);
    int rc = min(max(r, 0), SZ - 1);
    int cc = min(max(c, 0), SZ - 1);
    const float* q = ib + ((long long)rc * SZ + cc) * 3;
    float m = ok ? 1.0f : 0.0f;
    a = q[0] * m;
    b = q[1] * m;
    d = q[2] * m;
}

// ---------------------------------------------------------------------------
// feats kernel: one thread per (p, n, ij), ij in [0,25). Computes all 3
// channels for its crop position (one dwordx3 gather per corner covers all
// channels). Output layout: out[((p*16+n)*3 + c)*25 + ij].
// ---------------------------------------------------------------------------
__global__ __launch_bounds__(256) void feats_kernel(const float* __restrict__ pts,
                                                    const float* __restrict__ imgs,
                                                    const float* __restrict__ km,
                                                    float* __restrict__ out) {
    unsigned tid = blockIdx.x * 256u + threadIdx.x;  // 26,214,400 threads exactly
    unsigned ij = tid % 25u;
    unsigned pn = tid / 25u;
    unsigned n  = pn & (NVIEWS - 1);
    unsigned p  = pn >> 4;

    // projection (uniform across the 25 threads of a pn-group; cheap to redo)
    float px = pts[3 * p], py = pts[3 * p + 1], pz = pts[3 * p + 2];
    const float* k = km + n * 12;
    float psx = k[0] * px + k[1] * py + k[2]  * pz + k[3];
    float psy = k[4] * px + k[5] * py + k[6]  * pz + k[7];
    float psz = k[8] * px + k[9] * py + k[10] * pz + k[11];
    float inv = __builtin_amdgcn_rcpf(psz);
    float u = psx * inv * (1.0f / SZ);
    float v = psy * inv * (1.0f / SZ);
    u = fminf(fmaxf(u, 0.0f), 1.0f);
    v = fminf(fmaxf(v, 0.0f), 1.0f);
    float x = u * SZ + (float)(PAD - 2);  // + PADDING - CROP_STEP
    float y = v * SZ + (float)(PAD - 2);

    int i = (int)(ij / 5u);
    int j = (int)(ij % 5u);

    float r  = (x + (float)i) * SCALE;
    float cc = (y + (float)j) * SCALE;
    float r0f = floorf(r);
    float c0f = floorf(cc);
    float wr = r - r0f;
    float wc = cc - c0f;
    int r0 = (int)r0f - PAD;  // original-image row of corner 00
    int c0 = (int)c0f - PAD;

    const float* ib = imgs + (long long)n * (SZ * SZ * 3);
    float a00, b00, d00, a01, b01, d01, a10, b10, d10, a11, b11, d11;
    fetch3(ib, r0,     c0,     a00, b00, d00);
    fetch3(ib, r0,     c0 + 1, a01, b01, d01);
    fetch3(ib, r0 + 1, c0,     a10, b10, d10);
    fetch3(ib, r0 + 1, c0 + 1, a11, b11, d11);

    float w00 = (1.0f - wr) * (1.0f - wc);
    float w01 = (1.0f - wr) * wc;
    float w10 = wr * (1.0f - wc);
    float w11 = wr * wc;

    float o0 = w00 * a00 + w01 * a01 + w10 * a10 + w11 * a11;
    float o1 = w00 * b00 + w01 * b01 + w10 * b10 + w11 * b11;
    float o2 = w00 * d00 + w01 * d01 + w10 * d10 + w11 * d11;

    float* ob = out + (long long)pn * 75 + ij;
    ob[0]  = o0;
    ob[25] = o1;
    ob[50] = o2;
}

// ---------------------------------------------------------------------------
// coord_norm kernel: out2[n][p][0..1] = 2*clip(ps.xy/ps.z/SZ,0,1) - 1
// tid = n*NPTS + p so consecutive threads write consecutive float2.
// ---------------------------------------------------------------------------
__global__ __launch_bounds__(256) void coord_kernel(const float* __restrict__ pts,
                                                    const float* __restrict__ km,
                                                    float* __restrict__ out2) {
    unsigned tid = blockIdx.x * 256u + threadIdx.x;  // 1,048,576 threads exactly
    unsigned p = tid & (NPTS - 1);
    unsigned n = tid >> 16;

    float px = pts[3 * p], py = pts[3 * p + 1], pz = pts[3 * p + 2];
    const float* k = km + n * 12;
    float psx = k[0] * px + k[1] * py + k[2]  * pz + k[3];
    float psy = k[4] * px + k[5] * py + k[6]  * pz + k[7];
    float psz = k[8] * px + k[9] * py + k[10] * pz + k[11];
    float inv = __builtin_amdgcn_rcpf(psz);
    float u = psx * inv * (1.0f / SZ);
    float v = psy * inv * (1.0f / SZ);
    u = fminf(fmaxf(u, 0.0f), 1.0f);
    v = fminf(fmaxf(v, 0.0f), 1.0f);

    float2* o = (float2*)out2;
    o[tid] = make_float2(2.0f * u - 1.0f, 2.0f * v - 1.0f);
}

extern "C" void kernel_launch(void* const* d_in, const int* in_sizes, int n_in,
                              void* d_out, int out_size, void* d_ws, size_t ws_size,
                              hipStream_t stream) {
    const float* points = (const float*)d_in[0];  // (65536, 3)
    const float* images = (const float*)d_in[1];  // (16, 400, 400, 3)
    const float* poses  = (const float*)d_in[2];  // (16, 4, 4)
    float* out = (float*)d_out;
    float* km  = (float*)d_ws;  // 16 * 12 floats

    setup_km<<<1, 64, 0, stream>>>(poses, km);

    // feats: 65536*16*25 = 26,214,400 threads = 102,400 blocks of 256
    feats_kernel<<<102400, 256, 0, stream>>>(points, images, km, out);

    // coord_norm: 16*65536 = 1,048,576 threads = 4096 blocks of 256
    coord_kernel<<<4096, 256, 0, stream>>>(points, km, out + FEATS_N);
}

// Round 3
// 431.418 us; speedup vs baseline: 1.1089x; 1.1089x over previous
//
#include <hip/hip_runtime.h>

// Problem constants (from reference)
constexpr int   NPTS   = 65536;
constexpr int   NVIEWS = 16;
constexpr int   SZ     = 400;          // IMG_SIZE
constexpr int   PAD    = 5;            // PADDING
constexpr float FOCAL  = 555.555f;
constexpr float SCALE  = 409.0f / 410.0f;  // (Hp-1)/Hp

constexpr long long FEATS_N = (long long)NPTS * NVIEWS * 3 * 25;  // 78,643,200

typedef float vfloat2 __attribute__((ext_vector_type(2)));  // native clang vector
                                                            // (HIP float2 is a class
                                                            //  -> rejected by
                                                            //  __builtin_nontemporal_store)

// ---------------------------------------------------------------------------
// Setup: per-view combined projection KM = K @ inv(pose @ flip)[:3,:]
// pose is rigid: c2w = [x|y|z|t; 0 0 0 1], flip negates column 0.
// A = pose@flip = [(-x)|y|z|t], A3 orthonormal -> inv(A) = [A3^T | -A3^T t].
// ---------------------------------------------------------------------------
__global__ void setup_km(const float* __restrict__ poses, float* __restrict__ km) {
    int n = threadIdx.x;
    if (n >= NVIEWS) return;
    const float* A = poses + n * 16;  // row-major 4x4
    float x0 = A[0], x1 = A[4], x2 = A[8];
    float y0 = A[1], y1 = A[5], y2 = A[9];
    float z0 = A[2], z1 = A[6], z2 = A[10];
    float t0 = A[3], t1 = A[7], t2 = A[11];

    float M0[4] = { -x0, -x1, -x2,  (x0 * t0 + x1 * t1 + x2 * t2) };
    float M1[4] = {  y0,  y1,  y2, -(y0 * t0 + y1 * t1 + y2 * t2) };
    float M2[4] = {  z0,  z1,  z2, -(z0 * t0 + z1 * t1 + z2 * t2) };

    const float f = FOCAL, cx = 0.5f * SZ;
    float* o = km + n * 12;
#pragma unroll
    for (int k = 0; k < 4; ++k) o[k]     = f * M0[k] + cx * M2[k];
#pragma unroll
    for (int k = 0; k < 4; ++k) o[4 + k] = f * M1[k] + cx * M2[k];
#pragma unroll
    for (int k = 0; k < 4; ++k) o[8 + k] = M2[k];
}

// ---------------------------------------------------------------------------
// Gated 3-channel fetch from the (conceptually padded) image.
// r,c are ORIGINAL-image indices (padded index minus PAD). Out of [0,400)
// means padding -> 0. The reference's extra valid mask (ri in [0,410)) is
// always true for clipped projections, so it is omitted.
// ---------------------------------------------------------------------------
__device__ __forceinline__ void fetch3(const float* __restrict__ ib, int r, int c,
                                       float& a, float& b, float& d) {
    bool ok = ((unsigned)r < (unsigned)SZ) & ((unsigned)c < (unsigned)SZ);
    int rc = min(max(r, 0), SZ - 1);
    int cc = min(max(c, 0), SZ - 1);
    const float* q = ib + ((long long)rc * SZ + cc) * 3;
    float m = ok ? 1.0f : 0.0f;
    a = q[0] * m;
    b = q[1] * m;
    d = q[2] * m;
}

// ---------------------------------------------------------------------------
// feats kernel, view-partitioned + XCD-swizzled:
//   block b -> view n = (b&7) + 8*((b>>3)&1)   (XCD = b%8 empirically, so each
//   XCD's gather working set is 2 views = 3.84 MB <= 4 MiB L2)
//   chunk  = b >> 4 in [0, 6400); per-view task idx = chunk*256 + tid
//   idx in [0, 65536*25): p = idx/25, ij = idx%25.
// One thread per (p, n, ij), computes all 3 channels (dwordx3 gather per
// corner covers all channels). Output: out[((p*16+n)*3 + c)*25 + ij], written
// non-temporally (write-once stream; keep it out of L2).
// ---------------------------------------------------------------------------
__global__ __launch_bounds__(256) void feats_kernel(const float* __restrict__ pts,
                                                    const float* __restrict__ imgs,
                                                    const float* __restrict__ km,
                                                    float* __restrict__ out) {
    unsigned b   = blockIdx.x;
    unsigned n   = (b & 7u) + 8u * ((b >> 3) & 1u);
    unsigned idx = (b >> 4) * 256u + threadIdx.x;   // [0, 1,638,400)
    unsigned p   = idx / 25u;
    unsigned ij  = idx % 25u;

    float px = pts[3 * p], py = pts[3 * p + 1], pz = pts[3 * p + 2];
    const float* k = km + n * 12;
    float psx = k[0] * px + k[1] * py + k[2]  * pz + k[3];
    float psy = k[4] * px + k[5] * py + k[6]  * pz + k[7];
    float psz = k[8] * px + k[9] * py + k[10] * pz + k[11];
    float inv = __builtin_amdgcn_rcpf(psz);
    float u = psx * inv * (1.0f / SZ);
    float v = psy * inv * (1.0f / SZ);
    u = fminf(fmaxf(u, 0.0f), 1.0f);
    v = fminf(fmaxf(v, 0.0f), 1.0f);
    float x = u * SZ + (float)(PAD - 2);  // + PADDING - CROP_STEP
    float y = v * SZ + (float)(PAD - 2);

    int i = (int)(ij / 5u);
    int j = (int)(ij % 5u);

    float r  = (x + (float)i) * SCALE;
    float cc = (y + (float)j) * SCALE;
    float r0f = floorf(r);
    float c0f = floorf(cc);
    float wr = r - r0f;
    float wc = cc - c0f;
    int r0 = (int)r0f - PAD;  // original-image row of corner 00
    int c0 = (int)c0f - PAD;

    const float* ib = imgs + (long long)n * (SZ * SZ * 3);
    float a00, b00, d00, a01, b01, d01, a10, b10, d10, a11, b11, d11;
    fetch3(ib, r0,     c0,     a00, b00, d00);
    fetch3(ib, r0,     c0 + 1, a01, b01, d01);
    fetch3(ib, r0 + 1, c0,     a10, b10, d10);
    fetch3(ib, r0 + 1, c0 + 1, a11, b11, d11);

    float w00 = (1.0f - wr) * (1.0f - wc);
    float w01 = (1.0f - wr) * wc;
    float w10 = wr * (1.0f - wc);
    float w11 = wr * wc;

    float o0 = w00 * a00 + w01 * a01 + w10 * a10 + w11 * a11;
    float o1 = w00 * b00 + w01 * b01 + w10 * b10 + w11 * b11;
    float o2 = w00 * d00 + w01 * d01 + w10 * d10 + w11 * d11;

    unsigned pn = p * 16u + n;
    float* ob = out + (long long)pn * 75 + ij;
    __builtin_nontemporal_store(o0, &ob[0]);
    __builtin_nontemporal_store(o1, &ob[25]);
    __builtin_nontemporal_store(o2, &ob[50]);
}

// ---------------------------------------------------------------------------
// coord_norm kernel: out2[n][p][0..1] = 2*clip(ps.xy/ps.z/SZ,0,1) - 1
// ---------------------------------------------------------------------------
__global__ __launch_bounds__(256) void coord_kernel(const float* __restrict__ pts,
                                                    const float* __restrict__ km,
                                                    float* __restrict__ out2) {
    unsigned tid = blockIdx.x * 256u + threadIdx.x;  // 1,048,576 threads exactly
    unsigned p = tid & (NPTS - 1);
    unsigned n = tid >> 16;

    float px = pts[3 * p], py = pts[3 * p + 1], pz = pts[3 * p + 2];
    const float* k = km + n * 12;
    float psx = k[0] * px + k[1] * py + k[2]  * pz + k[3];
    float psy = k[4] * px + k[5] * py + k[6]  * pz + k[7];
    float psz = k[8] * px + k[9] * py + k[10] * pz + k[11];
    float inv = __builtin_amdgcn_rcpf(psz);
    float u = psx * inv * (1.0f / SZ);
    float v = psy * inv * (1.0f / SZ);
    u = fminf(fmaxf(u, 0.0f), 1.0f);
    v = fminf(fmaxf(v, 0.0f), 1.0f);

    vfloat2* o = (vfloat2*)out2;
    vfloat2 val = { 2.0f * u - 1.0f, 2.0f * v - 1.0f };
    __builtin_nontemporal_store(val, &o[tid]);
}

extern "C" void kernel_launch(void* const* d_in, const int* in_sizes, int n_in,
                              void* d_out, int out_size, void* d_ws, size_t ws_size,
                              hipStream_t stream) {
    const float* points = (const float*)d_in[0];  // (65536, 3)
    const float* images = (const float*)d_in[1];  // (16, 400, 400, 3)
    const float* poses  = (const float*)d_in[2];  // (16, 4, 4)
    float* out = (float*)d_out;
    float* km  = (float*)d_ws;  // 16 * 12 floats

    setup_km<<<1, 64, 0, stream>>>(poses, km);

    // feats: 16 views * 6400 chunks = 102,400 blocks of 256
    feats_kernel<<<102400, 256, 0, stream>>>(points, images, km, out);

    // coord_norm: 16*65536 = 1,048,576 threads = 4096 blocks of 256
    coord_kernel<<<4096, 256, 0, stream>>>(points, km, out + FEATS_N);
}